// Round 6
// baseline (2196.047 us; speedup 1.0000x reference)
//
#include <hip/hip_runtime.h>
#include <hip/hip_bf16.h>

#define Hh   64      // LSTM hidden
#define G4   256     // 4*H gate width
#define Dd   128     // input feature dim
#define Bsz  256     // batch
#define Tt   1024    // time steps
#define NOUT 10      // dense classes

typedef __bf16  bf16x8 __attribute__((ext_vector_type(8)));
typedef float   f32x4v __attribute__((ext_vector_type(4)));

// Gate-column permutation: z-row rho <-> (gate g, h-index hidx) chosen so the
// 16x16x32 D-fragment (row=(l>>4)*4+r, col=l&15) lands all 4 gates of
// hidx = 32s + 8kq + 4d2 + dl in lane l = kq*16+m, which is exactly the lane
// that must hold h[hidx] for the next step's B-fragment (k=(l>>4)*8+j).
//   rho = 64g + 32s + 16d2 + 4kq + dl ;  hidx = 32s + 8kq + 4d2 + dl
__device__ __forceinline__ int rho_origcol(int rho) {
    const int g  = rho >> 6;
    const int s  = (rho >> 5) & 1;
    const int d2 = (rho >> 4) & 1;
    const int kq = (rho >> 2) & 3;
    const int dl = rho & 3;
    return g * 64 + (32 * s + 8 * kq + 4 * d2 + dl);
}

// ---------------------------------------------------------------------------
// K0: Wt[rho][k] = bf16(scale * W[k][origcol]), bias2[rho] = scale*b + offs.
// scale = 0.2 for i,f,o gates (hard-sigmoid pre-scale), 1 for g gate;
// offs = 0.5 for i,f,o so k2's clamp is a single med3.
// ---------------------------------------------------------------------------
__global__ __launch_bounds__(128)
void k0_prep(const float* __restrict__ W, const float* __restrict__ b,
             __bf16* __restrict__ Wt, float* __restrict__ bias2) {
    const int rho = blockIdx.x;   // 0..255
    const int k   = threadIdx.x;  // 0..127
    const int col = rho_origcol(rho);
    const bool isg = ((rho >> 6) == 2);
    const float sc = isg ? 1.f : 0.2f;
    Wt[(size_t)rho * Dd + k] = (__bf16)(sc * W[(size_t)k * G4 + col]);
    if (k == 0) bias2[rho] = sc * b[col] + (isg ? 0.f : 0.5f);
}

// ---------------------------------------------------------------------------
// K1: xw = x @ Wt + bias2 via mfma_f32_16x16x32_bf16 (cols are rho-permuted,
// pre-scaled; k1 itself is oblivious). Block = 4 waves = 128 rows x 256 cols.
// ---------------------------------------------------------------------------
#define K1_RT 8   // 16-row tiles per block -> 128 rows/block

__global__ __launch_bounds__(256)
void k1_mfma(const float* __restrict__ x, const __bf16* __restrict__ Wt,
             const float* __restrict__ bias, __bf16* __restrict__ xw) {
    const int tid = threadIdx.x;
    const int w   = tid >> 6;      // wave 0..3
    const int l   = tid & 63;
    const int r16 = l & 15;
    const int kq  = l >> 4;        // 0..3
    const size_t rowbase = (size_t)blockIdx.x * (16 * K1_RT);

    bf16x8 bfr[4][4];
    float  bval[4];
#pragma unroll
    for (int ct = 0; ct < 4; ++ct) {
        const int col = w * 64 + ct * 16 + r16;
        const __bf16* wp = Wt + (size_t)col * Dd + kq * 8;
#pragma unroll
        for (int kk = 0; kk < 4; ++kk)
            bfr[ct][kk] = *(const bf16x8*)(wp + kk * 32);
        bval[ct] = bias[col];
    }

    for (int rt = 0; rt < K1_RT; ++rt) {
        const size_t arow = rowbase + rt * 16 + r16;
        const float* xr = x + arow * Dd + kq * 8;
        bf16x8 afr[4];
#pragma unroll
        for (int kk = 0; kk < 4; ++kk) {
            const float4 lo = *(const float4*)(xr + kk * 32);
            const float4 hi = *(const float4*)(xr + kk * 32 + 4);
            afr[kk][0] = (__bf16)lo.x; afr[kk][1] = (__bf16)lo.y;
            afr[kk][2] = (__bf16)lo.z; afr[kk][3] = (__bf16)lo.w;
            afr[kk][4] = (__bf16)hi.x; afr[kk][5] = (__bf16)hi.y;
            afr[kk][6] = (__bf16)hi.z; afr[kk][7] = (__bf16)hi.w;
        }
        f32x4v acc[4];
#pragma unroll
        for (int ct = 0; ct < 4; ++ct)
            acc[ct] = (f32x4v){bval[ct], bval[ct], bval[ct], bval[ct]};
#pragma unroll
        for (int ct = 0; ct < 4; ++ct)
#pragma unroll
            for (int kk = 0; kk < 4; ++kk)
                acc[ct] = __builtin_amdgcn_mfma_f32_16x16x32_bf16(
                              afr[kk], bfr[ct][kk], acc[ct], 0, 0, 0);

        const size_t orow0 = rowbase + rt * 16 + kq * 4;
#pragma unroll
        for (int ct = 0; ct < 4; ++ct) {
            const int col = w * 64 + ct * 16 + r16;
#pragma unroll
            for (int rr = 0; rr < 4; ++rr)
                xw[(orow0 + rr) * G4 + col] = (__bf16)acc[ct][rr];
        }
    }
}

// ---------------------------------------------------------------------------
// K2: LSTM scan, ONE WAVE per 16-batch group (16 blocks x 64 threads).
// No LDS, no barriers, no cross-lane ops in the loop: the rho permutation
// makes gate math and the next-step B-fragment fully lane-local.
//   A (AGPR-resident, const): au[tt][ks] = 0.2-prescaled Ut tile frags
//   B: bh0/bh1 = bf16(h) packed by this lane last step
//   C: unpacked from depth-2 prefetched xw (bf16 dwords -> f32 via shl/and)
// ---------------------------------------------------------------------------
__global__ __launch_bounds__(64)
void k2_scan(const __bf16* __restrict__ xw, const float* __restrict__ U,
             float* __restrict__ hout) {
    const int l  = threadIdx.x & 63;
    const int kq = l >> 4;         // A/B k-quad
    const int m  = l & 15;         // batch within group / A-row / B-col
    const int b0 = blockIdx.x * 16;

    // A-frags: au[tt][ks][j] = sc * U[ks*32 + kq*8 + j][origcol(16tt + m)]
    bf16x8 au[16][2];
#pragma unroll
    for (int tt = 0; tt < 16; ++tt) {
        const int rho = 16 * tt + m;
        const int col = rho_origcol(rho);
        const float sc = ((rho >> 6) == 2) ? 1.f : 0.2f;
#pragma unroll
        for (int ks = 0; ks < 2; ++ks)
#pragma unroll
            for (int j = 0; j < 8; ++j)
                au[tt][ks][j] = (__bf16)(sc * U[(size_t)(ks * 32 + kq * 8 + j) * G4 + col]);
    }

    float c[2][2][4];
    float h[2][2][4];
#pragma unroll
    for (int s = 0; s < 2; ++s)
#pragma unroll
        for (int d2 = 0; d2 < 2; ++d2)
#pragma unroll
            for (int dl = 0; dl < 4; ++dl) { c[s][d2][dl] = 0.f; h[s][d2][dl] = 0.f; }

    bf16x8 bh0 = {};   // h == 0 at t=0
    bf16x8 bh1 = {};

    // per-lane xw base: row (b0+m), byte offset kq*8 within the 512B row
    const char* pbase = (const char*)xw + ((size_t)(b0 + m) * Tt) * (G4 * 2) + kq * 8;

    // prefetch depth 2 (dead prefetches at the tail read into hbuf: in-bounds of ws)
    uint2 pf[2][16];
#pragma unroll
    for (int s = 0; s < 2; ++s)
#pragma unroll
        for (int tt = 0; tt < 16; ++tt)
            pf[s][tt] = *(const uint2*)(pbase + s * 512 + tt * 32);

    for (int t0 = 0; t0 < Tt; t0 += 2) {
        const char* pc = pbase + (size_t)t0 * 512;
#pragma unroll
        for (int s = 0; s < 2; ++s) {
            // ---- C init: unpack bf16 pairs (shl16 / and) — exact f32
            f32x4v acc[16];
#pragma unroll
            for (int tt = 0; tt < 16; ++tt) {
                const uint2 d = pf[s][tt];
                acc[tt][0] = __builtin_bit_cast(float, d.x << 16);
                acc[tt][1] = __builtin_bit_cast(float, d.x & 0xFFFF0000u);
                acc[tt][2] = __builtin_bit_cast(float, d.y << 16);
                acc[tt][3] = __builtin_bit_cast(float, d.y & 0xFFFF0000u);
            }
            // ---- refill this slot for step t0+s+2 (imm offsets off pc)
#pragma unroll
            for (int tt = 0; tt < 16; ++tt)
                pf[s][tt] = *(const uint2*)(pc + (s + 2) * 512 + tt * 32);

            // ---- z' = 0.2*(h.U) [+ xw'] : 32 MFMA, A in AGPRs, B in regs
#pragma unroll
            for (int tt = 0; tt < 16; ++tt) {
                acc[tt] = __builtin_amdgcn_mfma_f32_16x16x32_bf16(au[tt][0], bh0, acc[tt], 0, 0, 0);
                acc[tt] = __builtin_amdgcn_mfma_f32_16x16x32_bf16(au[tt][1], bh1, acc[tt], 0, 0, 0);
            }

            // ---- gates: all register-local. z'_ifo already 0.2z+0.5.
#pragma unroll
            for (int s2 = 0; s2 < 2; ++s2)
#pragma unroll
                for (int d2 = 0; d2 < 2; ++d2) {
                    const int ti = 2 * s2 + d2;
#pragma unroll
                    for (int dl = 0; dl < 4; ++dl) {
                        const float gi = fminf(fmaxf(acc[ti][dl],      0.f), 1.f);  // med3
                        const float gf = fminf(fmaxf(acc[4 + ti][dl],  0.f), 1.f);
                        const float gg = fmaxf(acc[8 + ti][dl], 0.f);
                        const float go = fminf(fmaxf(acc[12 + ti][dl], 0.f), 1.f);
                        const float cc = fmaf(gf, c[s2][d2][dl], gi * gg);
                        c[s2][d2][dl] = cc;
                        h[s2][d2][dl] = go * fmaxf(cc, 0.f);
                    }
                }

            // ---- pack next-step B-frags: bh0 = h[s=0], bh1 = h[s=1]
#pragma unroll
            for (int d2 = 0; d2 < 2; ++d2)
#pragma unroll
                for (int dl = 0; dl < 4; ++dl) {
                    bh0[4 * d2 + dl] = (__bf16)h[0][d2][dl];
                    bh1[4 * d2 + dl] = (__bf16)h[1][d2][dl];
                }
        }
    }

    // final h: hidx = 32*s2 + 8*kq + 4*d2 + dl
#pragma unroll
    for (int s2 = 0; s2 < 2; ++s2)
#pragma unroll
        for (int d2 = 0; d2 < 2; ++d2)
#pragma unroll
            for (int dl = 0; dl < 4; ++dl)
                hout[(size_t)(b0 + m) * Hh + 32 * s2 + 8 * kq + 4 * d2 + dl] = h[s2][d2][dl];
}

// ---------------------------------------------------------------------------
// K3: out[r,:] = softmax(h[r,:] @ Wd + bd). One block, thread = batch row.
// ---------------------------------------------------------------------------
__global__ __launch_bounds__(256)
void k3_dense(const float* __restrict__ hin, const float* __restrict__ Wd,
              const float* __restrict__ bd, float* __restrict__ out) {
    __shared__ float wd[Hh * NOUT];
    __shared__ float bds[NOUT];
    for (int i = threadIdx.x; i < Hh * NOUT; i += blockDim.x) wd[i] = Wd[i];
    if (threadIdx.x < NOUT) bds[threadIdx.x] = bd[threadIdx.x];
    __syncthreads();

    const int r = threadIdx.x;
    if (r < Bsz) {
        float hrow[Hh];
#pragma unroll
        for (int j = 0; j < Hh; ++j) hrow[j] = hin[(size_t)r * Hh + j];
        float logits[NOUT];
#pragma unroll
        for (int o = 0; o < NOUT; ++o) {
            float acc = bds[o];
#pragma unroll
            for (int j = 0; j < Hh; ++j) acc = fmaf(hrow[j], wd[j * NOUT + o], acc);
            logits[o] = acc;
        }
        float mx = logits[0];
#pragma unroll
        for (int o = 1; o < NOUT; ++o) mx = fmaxf(mx, logits[o]);
        float s = 0.f;
#pragma unroll
        for (int o = 0; o < NOUT; ++o) { logits[o] = expf(logits[o] - mx); s += logits[o]; }
        const float inv = 1.f / s;
#pragma unroll
        for (int o = 0; o < NOUT; ++o) out[(size_t)r * NOUT + o] = logits[o] * inv;
    }
}

// ---------------------------------------------------------------------------
extern "C" void kernel_launch(void* const* d_in, const int* in_sizes, int n_in,
                              void* d_out, int out_size, void* d_ws, size_t ws_size,
                              hipStream_t stream) {
    const float* x  = (const float*)d_in[0];
    const float* W  = (const float*)d_in[1];
    const float* U  = (const float*)d_in[2];
    const float* b  = (const float*)d_in[3];
    const float* Wd = (const float*)d_in[4];
    const float* bd = (const float*)d_in[5];
    float* out = (float*)d_out;

    const size_t xw_bytes = (size_t)Bsz * Tt * G4 * sizeof(__bf16);   // 128 MiB
    __bf16* xw    = (__bf16*)d_ws;
    float*  hbuf  = (float*)((char*)d_ws + xw_bytes);                 // 64 KB
    __bf16* Wt    = (__bf16*)((char*)hbuf + (size_t)Bsz * Hh * sizeof(float));
    float*  bias2 = (float*)((char*)Wt + (size_t)G4 * Dd * sizeof(__bf16));

    k0_prep<<<G4, Dd, 0, stream>>>(W, b, Wt, bias2);
    k1_mfma<<<(Bsz * Tt) / (16 * K1_RT), 256, 0, stream>>>(x, Wt, bias2, xw);
    k2_scan<<<Bsz / 16, 64, 0, stream>>>(xw, U, hbuf);
    k3_dense<<<1, 256, 0, stream>>>(hbuf, Wd, bd, out);
}

// Round 7
// 1490.233 us; speedup vs baseline: 1.4736x; 1.4736x over previous
//
#include <hip/hip_runtime.h>
#include <hip/hip_bf16.h>

#define Hh   64      // LSTM hidden
#define G4   256     // 4*H gate width
#define Dd   128     // input feature dim
#define Bsz  256     // batch
#define Tt   1024    // time steps
#define NOUT 10      // dense classes

typedef __bf16  bf16x8 __attribute__((ext_vector_type(8)));
typedef float   f32x4v __attribute__((ext_vector_type(4)));

// Gate-column permutation: z-row rho <-> (gate g, h-index hidx) chosen so the
// 16x16x32 D-fragment (row=(l>>4)*4+r, col=l&15) lands all 4 gates of
// hidx = 32s + 8kq + 4d2 + dl in lane l = kq*16+m == the lane that must hold
// h[hidx] for the next step's B-fragment (k=(l>>4)*8+j).
//   rho = 64g + 32s + 16d2 + 4kq + dl ;  hidx = 32s + 8kq + 4d2 + dl
__device__ __forceinline__ int rho_origcol(int rho) {
    const int g  = rho >> 6;
    const int s  = (rho >> 5) & 1;
    const int d2 = (rho >> 4) & 1;
    const int kq = (rho >> 2) & 3;
    const int dl = rho & 3;
    return g * 64 + (32 * s + 8 * kq + 4 * d2 + dl);
}

// xws layout (k2-native, bf16):
//   byte(b, t, rho) = (b>>4)*8MB + t*8192 + (rho>>5)*1024
//                     + ((rho>>2)&3)*256 + (b&15)*16 + ((rho>>4)&1)*8 + (rho&3)*2
// so lane l = kq*16+m of group g16 reads ONE contiguous 16B (uint4) per ttp:
//   [tt=2ttp: rho 32ttp+4kq+0..3][tt=2ttp+1: rho +16 ...], 8 loads x 1KB per step.

// ---------------------------------------------------------------------------
// K0: Wt[rho][k] = bf16(scale * W[k][origcol]), bias2[rho] = scale*b + offs.
// scale = 0.2 for i,f,o gates (hard-sigmoid pre-scale), 1 for g gate.
// ---------------------------------------------------------------------------
__global__ __launch_bounds__(128)
void k0_prep(const float* __restrict__ W, const float* __restrict__ b,
             __bf16* __restrict__ Wt, float* __restrict__ bias2) {
    const int rho = blockIdx.x;   // 0..255
    const int k   = threadIdx.x;  // 0..127
    const int col = rho_origcol(rho);
    const bool isg = ((rho >> 6) == 2);
    const float sc = isg ? 1.f : 0.2f;
    Wt[(size_t)rho * Dd + k] = (__bf16)(sc * W[(size_t)k * G4 + col]);
    if (k == 0) bias2[rho] = sc * b[col] + (isg ? 0.f : 0.5f);
}

// ---------------------------------------------------------------------------
// K1: xw = x @ Wt + bias2 via mfma_f32_16x16x32_bf16, stored into the
// k2-native xws layout (2B scalar stores; regions L2-write-combine since one
// block covers each 8KB step-block for its batch).
// ---------------------------------------------------------------------------
#define K1_RT 8   // 16-row tiles per block -> 128 rows/block (one batch b per block)

__global__ __launch_bounds__(256)
void k1_mfma(const float* __restrict__ x, const __bf16* __restrict__ Wt,
             const float* __restrict__ bias, __bf16* __restrict__ xws) {
    const int tid = threadIdx.x;
    const int w   = tid >> 6;      // wave 0..3
    const int l   = tid & 63;
    const int r16 = l & 15;
    const int kq  = l >> 4;        // 0..3 (A-row quad)
    const size_t rowbase = (size_t)blockIdx.x * (16 * K1_RT);

    const int bb   = (int)(rowbase >> 10);      // batch (uniform per block)
    const size_t gm_base = ((size_t)(bb >> 4) << 23) + (size_t)(bb & 15) * 16;
    const int lane_off = (r16 >> 2) * 256 + (r16 & 3) * 2;

    bf16x8 bfr[4][4];
    float  bval[4];
#pragma unroll
    for (int ct = 0; ct < 4; ++ct) {
        const int col = w * 64 + ct * 16 + r16;
        const __bf16* wp = Wt + (size_t)col * Dd + kq * 8;
#pragma unroll
        for (int kk = 0; kk < 4; ++kk)
            bfr[ct][kk] = *(const bf16x8*)(wp + kk * 32);
        bval[ct] = bias[col];
    }

    for (int rt = 0; rt < K1_RT; ++rt) {
        const size_t arow = rowbase + rt * 16 + r16;
        const float* xr = x + arow * Dd + kq * 8;
        bf16x8 afr[4];
#pragma unroll
        for (int kk = 0; kk < 4; ++kk) {
            const float4 lo = *(const float4*)(xr + kk * 32);
            const float4 hi = *(const float4*)(xr + kk * 32 + 4);
            afr[kk][0] = (__bf16)lo.x; afr[kk][1] = (__bf16)lo.y;
            afr[kk][2] = (__bf16)lo.z; afr[kk][3] = (__bf16)lo.w;
            afr[kk][4] = (__bf16)hi.x; afr[kk][5] = (__bf16)hi.y;
            afr[kk][6] = (__bf16)hi.z; afr[kk][7] = (__bf16)hi.w;
        }
        f32x4v acc[4];
#pragma unroll
        for (int ct = 0; ct < 4; ++ct)
            acc[ct] = (f32x4v){bval[ct], bval[ct], bval[ct], bval[ct]};
#pragma unroll
        for (int ct = 0; ct < 4; ++ct)
#pragma unroll
            for (int kk = 0; kk < 4; ++kk)
                acc[ct] = __builtin_amdgcn_mfma_f32_16x16x32_bf16(
                              afr[kk], bfr[ct][kk], acc[ct], 0, 0, 0);

        // D row (M dim) = time t; D col = rho = w*64 + ct*16 + r16
        const int trow0 = (int)((rowbase + rt * 16 + kq * 4) & 1023);
#pragma unroll
        for (int ct = 0; ct < 4; ++ct) {
            // ct_off: ttp=(4w+ct)>>1 -> *1024 ; ttl=(ct&1) -> *8
            const size_t ct_off = (size_t)(2 * w + (ct >> 1)) * 1024 + (size_t)(ct & 1) * 8;
#pragma unroll
            for (int rr = 0; rr < 4; ++rr) {
                char* dst = (char*)xws + gm_base + (size_t)(trow0 + rr) * 8192
                            + ct_off + lane_off;
                *(__bf16*)dst = (__bf16)acc[ct][rr];
            }
        }
    }
}

// ---------------------------------------------------------------------------
// K2: LSTM scan, ONE WAVE per 16-batch group (16 blocks x 64 threads).
// No LDS, no barriers, no cross-lane ops. Per step: 8 coalesced dwordx4
// loads (depth-4 register ring, all indices static), 64 unpack ops,
// 32 MFMA (A = prescaled Ut, const), register-local gates, bf16 repack.
// ---------------------------------------------------------------------------
__global__ __launch_bounds__(64, 1)
void k2_scan(const __bf16* __restrict__ xws, const float* __restrict__ U,
             float* __restrict__ hout) {
    const int l  = threadIdx.x & 63;
    const int kq = l >> 4;
    const int m  = l & 15;
    const int b0 = blockIdx.x * 16;

    // A-frags: au[tt][ks][j] = sc * U[ks*32 + kq*8 + j][origcol(16tt + m)]
    bf16x8 au[16][2];
#pragma unroll
    for (int tt = 0; tt < 16; ++tt) {
        const int rho = 16 * tt + m;
        const int col = rho_origcol(rho);
        const float sc = ((rho >> 6) == 2) ? 1.f : 0.2f;
#pragma unroll
        for (int ks = 0; ks < 2; ++ks)
#pragma unroll
            for (int j = 0; j < 8; ++j)
                au[tt][ks][j] = (__bf16)(sc * U[(size_t)(ks * 32 + kq * 8 + j) * G4 + col]);
    }

    float c[2][2][4];
    float h[2][2][4];
#pragma unroll
    for (int s = 0; s < 2; ++s)
#pragma unroll
        for (int d2 = 0; d2 < 2; ++d2)
#pragma unroll
            for (int dl = 0; dl < 4; ++dl) { c[s][d2][dl] = 0.f; h[s][d2][dl] = 0.f; }

    bf16x8 bh0 = {};   // h == 0 at t=0
    bf16x8 bh1 = {};

    const char* gbase = (const char*)xws + ((size_t)blockIdx.x << 23) + (size_t)l * 16;

    // depth-4 prefetch ring, 8 x dwordx4 per step (each 1KB coalesced)
    uint4 pf[4][8];
#pragma unroll
    for (int d = 0; d < 4; ++d) {
        const char* p = gbase + (size_t)d * 8192;
#pragma unroll
        for (int tp = 0; tp < 8; ++tp)
            pf[d][tp] = *(const uint4*)(p + tp * 1024);
    }

    for (int t0 = 0; t0 < Tt; t0 += 4) {
#pragma unroll
        for (int s = 0; s < 4; ++s) {
            const int t = t0 + s;

            // ---- C init: unpack bf16 pairs (shl16 / and) — exact f32
            f32x4v acc[16];
#pragma unroll
            for (int tp = 0; tp < 8; ++tp) {
                const uint4 d = pf[s][tp];
                acc[2 * tp][0]     = __builtin_bit_cast(float, d.x << 16);
                acc[2 * tp][1]     = __builtin_bit_cast(float, d.x & 0xFFFF0000u);
                acc[2 * tp][2]     = __builtin_bit_cast(float, d.y << 16);
                acc[2 * tp][3]     = __builtin_bit_cast(float, d.y & 0xFFFF0000u);
                acc[2 * tp + 1][0] = __builtin_bit_cast(float, d.z << 16);
                acc[2 * tp + 1][1] = __builtin_bit_cast(float, d.z & 0xFFFF0000u);
                acc[2 * tp + 1][2] = __builtin_bit_cast(float, d.w << 16);
                acc[2 * tp + 1][3] = __builtin_bit_cast(float, d.w & 0xFFFF0000u);
            }

            // ---- refill this ring slot for step t+4 (coalesced)
            {
                int tpf = t + 4; if (tpf > Tt - 1) tpf = Tt - 1;
                const char* p = gbase + (size_t)tpf * 8192;
#pragma unroll
                for (int tp = 0; tp < 8; ++tp)
                    pf[s][tp] = *(const uint4*)(p + tp * 1024);
            }

            // ---- z' = Ut.h + xw' : 32 MFMA, 16 independent chains of 2
#pragma unroll
            for (int tt = 0; tt < 16; ++tt) {
                acc[tt] = __builtin_amdgcn_mfma_f32_16x16x32_bf16(au[tt][0], bh0, acc[tt], 0, 0, 0);
                acc[tt] = __builtin_amdgcn_mfma_f32_16x16x32_bf16(au[tt][1], bh1, acc[tt], 0, 0, 0);
            }

            // ---- gates: register-local; i,f,o are already 0.2z+0.5
#pragma unroll
            for (int s2 = 0; s2 < 2; ++s2)
#pragma unroll
                for (int d2 = 0; d2 < 2; ++d2) {
                    const int ti = 2 * s2 + d2;
#pragma unroll
                    for (int dl = 0; dl < 4; ++dl) {
                        const float gi = fminf(fmaxf(acc[ti][dl],      0.f), 1.f);  // med3
                        const float gf = fminf(fmaxf(acc[4 + ti][dl],  0.f), 1.f);
                        const float gg = fmaxf(acc[8 + ti][dl], 0.f);
                        const float go = fminf(fmaxf(acc[12 + ti][dl], 0.f), 1.f);
                        const float cc = fmaf(gf, c[s2][d2][dl], gi * gg);
                        c[s2][d2][dl] = cc;
                        h[s2][d2][dl] = go * fmaxf(cc, 0.f);
                    }
                }

            // ---- pack next-step B-frags: bh0 = h[s2=0], bh1 = h[s2=1]
#pragma unroll
            for (int d2 = 0; d2 < 2; ++d2)
#pragma unroll
                for (int dl = 0; dl < 4; ++dl) {
                    bh0[4 * d2 + dl] = (__bf16)h[0][d2][dl];
                    bh1[4 * d2 + dl] = (__bf16)h[1][d2][dl];
                }
        }
    }

    // final h: hidx = 32*s2 + 8*kq + 4*d2 + dl
#pragma unroll
    for (int s2 = 0; s2 < 2; ++s2)
#pragma unroll
        for (int d2 = 0; d2 < 2; ++d2)
#pragma unroll
            for (int dl = 0; dl < 4; ++dl)
                hout[(size_t)(b0 + m) * Hh + 32 * s2 + 8 * kq + 4 * d2 + dl] = h[s2][d2][dl];
}

// ---------------------------------------------------------------------------
// K3: out[r,:] = softmax(h[r,:] @ Wd + bd). One block, thread = batch row.
// ---------------------------------------------------------------------------
__global__ __launch_bounds__(256)
void k3_dense(const float* __restrict__ hin, const float* __restrict__ Wd,
              const float* __restrict__ bd, float* __restrict__ out) {
    __shared__ float wd[Hh * NOUT];
    __shared__ float bds[NOUT];
    for (int i = threadIdx.x; i < Hh * NOUT; i += blockDim.x) wd[i] = Wd[i];
    if (threadIdx.x < NOUT) bds[threadIdx.x] = bd[threadIdx.x];
    __syncthreads();

    const int r = threadIdx.x;
    if (r < Bsz) {
        float hrow[Hh];
#pragma unroll
        for (int j = 0; j < Hh; ++j) hrow[j] = hin[(size_t)r * Hh + j];
        float logits[NOUT];
#pragma unroll
        for (int o = 0; o < NOUT; ++o) {
            float acc = bds[o];
#pragma unroll
            for (int j = 0; j < Hh; ++j) acc = fmaf(hrow[j], wd[j * NOUT + o], acc);
            logits[o] = acc;
        }
        float mx = logits[0];
#pragma unroll
        for (int o = 1; o < NOUT; ++o) mx = fmaxf(mx, logits[o]);
        float s = 0.f;
#pragma unroll
        for (int o = 0; o < NOUT; ++o) { logits[o] = expf(logits[o] - mx); s += logits[o]; }
        const float inv = 1.f / s;
#pragma unroll
        for (int o = 0; o < NOUT; ++o) out[(size_t)r * NOUT + o] = logits[o] * inv;
    }
}

// ---------------------------------------------------------------------------
extern "C" void kernel_launch(void* const* d_in, const int* in_sizes, int n_in,
                              void* d_out, int out_size, void* d_ws, size_t ws_size,
                              hipStream_t stream) {
    const float* x  = (const float*)d_in[0];
    const float* W  = (const float*)d_in[1];
    const float* U  = (const float*)d_in[2];
    const float* b  = (const float*)d_in[3];
    const float* Wd = (const float*)d_in[4];
    const float* bd = (const float*)d_in[5];
    float* out = (float*)d_out;

    const size_t xw_bytes = (size_t)Bsz * Tt * G4 * sizeof(__bf16);   // 128 MiB
    __bf16* xws   = (__bf16*)d_ws;
    float*  hbuf  = (float*)((char*)d_ws + xw_bytes);                 // 64 KB
    __bf16* Wt    = (__bf16*)((char*)hbuf + (size_t)Bsz * Hh * sizeof(float));
    float*  bias2 = (float*)((char*)Wt + (size_t)G4 * Dd * sizeof(__bf16));

    k0_prep<<<G4, Dd, 0, stream>>>(W, b, Wt, bias2);
    k1_mfma<<<(Bsz * Tt) / (16 * K1_RT), 256, 0, stream>>>(x, Wt, bias2, xws);
    k2_scan<<<Bsz / 16, 64, 0, stream>>>(xws, U, hbuf);
    k3_dense<<<1, 256, 0, stream>>>(hbuf, Wd, bd, out);
}

// Round 8
// 1035.458 us; speedup vs baseline: 2.1208x; 1.4392x over previous
//
#include <hip/hip_runtime.h>
#include <hip/hip_bf16.h>

#define Hh   64      // LSTM hidden
#define G4   256     // 4*H gate width
#define Dd   128     // input feature dim
#define Bsz  256     // batch
#define Tt   1024    // time steps
#define NOUT 10      // dense classes

typedef __bf16  bf16x8 __attribute__((ext_vector_type(8)));
typedef float   f32x4v __attribute__((ext_vector_type(4)));

// Gate-column permutation: z-row rho <-> (gate g, h-index hidx) chosen so the
// 16x16x32 D-fragment (row=(l>>4)*4+r, col=l&15) lands all 4 gates of
// hidx = 32s + 8kq + 4d2 + dl in lane l = kq*16+m == the lane that must hold
// h[hidx] for the next step's B-fragment (k=(l>>4)*8+j).
//   rho = 64g + 32s + 16d2 + 4kq + dl ;  hidx = 32s + 8kq + 4d2 + dl
__device__ __forceinline__ int rho_origcol(int rho) {
    const int g  = rho >> 6;
    const int s  = (rho >> 5) & 1;
    const int d2 = (rho >> 4) & 1;
    const int kq = (rho >> 2) & 3;
    const int dl = rho & 3;
    return g * 64 + (32 * s + 8 * kq + 4 * d2 + dl);
}

// xws layout (k2-native, bf16):
//   byte(b, t, rho) = (b>>4)*8MB + t*8192 + (rho>>5)*1024
//                     + ((rho>>2)&3)*256 + (b&15)*16 + ((rho>>4)&1)*8 + (rho&3)*2
// lane l = kq*16+m of group g16 owns the contiguous 16B at
//   t*8192 + ttp*1024 + l*16  for ttp = 0..7  (8 x 1KB coalesced per step).

// async 16B/lane global->LDS DMA (wave-uniform LDS base + lane*16 dest)
__device__ __forceinline__ void gld_lds16(const void* g, void* l) {
    __builtin_amdgcn_global_load_lds(
        (const __attribute__((address_space(1))) unsigned int*)g,
        (__attribute__((address_space(3))) unsigned int*)l, 16, 0, 0);
}

// ---------------------------------------------------------------------------
// K0: Wt[rho][k] = bf16(scale * W[k][origcol]), bias2[rho] = scale*b + offs.
// scale = 0.2 for i,f,o gates (hard-sigmoid pre-scale), 1 for g gate.
// ---------------------------------------------------------------------------
__global__ __launch_bounds__(128)
void k0_prep(const float* __restrict__ W, const float* __restrict__ b,
             __bf16* __restrict__ Wt, float* __restrict__ bias2) {
    const int rho = blockIdx.x;   // 0..255
    const int k   = threadIdx.x;  // 0..127
    const int col = rho_origcol(rho);
    const bool isg = ((rho >> 6) == 2);
    const float sc = isg ? 1.f : 0.2f;
    Wt[(size_t)rho * Dd + k] = (__bf16)(sc * W[(size_t)k * G4 + col]);
    if (k == 0) bias2[rho] = sc * b[col] + (isg ? 0.f : 0.5f);
}

// ---------------------------------------------------------------------------
// K1: xw = x @ Wt + bias2 via mfma_f32_16x16x32_bf16, stored into the
// k2-native xws layout (2B scalar stores; L2 write-combines — each 8KB
// step-block is covered by one block).
// ---------------------------------------------------------------------------
#define K1_RT 8   // 16-row tiles per block -> 128 rows/block (one batch b per block)

__global__ __launch_bounds__(256)
void k1_mfma(const float* __restrict__ x, const __bf16* __restrict__ Wt,
             const float* __restrict__ bias, __bf16* __restrict__ xws) {
    const int tid = threadIdx.x;
    const int w   = tid >> 6;      // wave 0..3
    const int l   = tid & 63;
    const int r16 = l & 15;
    const int kq  = l >> 4;        // 0..3 (A-row quad)
    const size_t rowbase = (size_t)blockIdx.x * (16 * K1_RT);

    const int bb   = (int)(rowbase >> 10);      // batch (uniform per block)
    const size_t gm_base = ((size_t)(bb >> 4) << 23) + (size_t)(bb & 15) * 16;
    const int lane_off = (r16 >> 2) * 256 + (r16 & 3) * 2;

    bf16x8 bfr[4][4];
    float  bval[4];
#pragma unroll
    for (int ct = 0; ct < 4; ++ct) {
        const int col = w * 64 + ct * 16 + r16;
        const __bf16* wp = Wt + (size_t)col * Dd + kq * 8;
#pragma unroll
        for (int kk = 0; kk < 4; ++kk)
            bfr[ct][kk] = *(const bf16x8*)(wp + kk * 32);
        bval[ct] = bias[col];
    }

    for (int rt = 0; rt < K1_RT; ++rt) {
        const size_t arow = rowbase + rt * 16 + r16;
        const float* xr = x + arow * Dd + kq * 8;
        bf16x8 afr[4];
#pragma unroll
        for (int kk = 0; kk < 4; ++kk) {
            const float4 lo = *(const float4*)(xr + kk * 32);
            const float4 hi = *(const float4*)(xr + kk * 32 + 4);
            afr[kk][0] = (__bf16)lo.x; afr[kk][1] = (__bf16)lo.y;
            afr[kk][2] = (__bf16)lo.z; afr[kk][3] = (__bf16)lo.w;
            afr[kk][4] = (__bf16)hi.x; afr[kk][5] = (__bf16)hi.y;
            afr[kk][6] = (__bf16)hi.z; afr[kk][7] = (__bf16)hi.w;
        }
        f32x4v acc[4];
#pragma unroll
        for (int ct = 0; ct < 4; ++ct)
            acc[ct] = (f32x4v){bval[ct], bval[ct], bval[ct], bval[ct]};
#pragma unroll
        for (int ct = 0; ct < 4; ++ct)
#pragma unroll
            for (int kk = 0; kk < 4; ++kk)
                acc[ct] = __builtin_amdgcn_mfma_f32_16x16x32_bf16(
                              afr[kk], bfr[ct][kk], acc[ct], 0, 0, 0);

        // D row (M dim) = time t; D col = rho = w*64 + ct*16 + r16
        const int trow0 = (int)((rowbase + rt * 16 + kq * 4) & 1023);
#pragma unroll
        for (int ct = 0; ct < 4; ++ct) {
            // ct_off: ttp=(4w+ct)>>1 -> *1024 ; (ct&1) -> *8
            const size_t ct_off = (size_t)(2 * w + (ct >> 1)) * 1024 + (size_t)(ct & 1) * 8;
#pragma unroll
            for (int rr = 0; rr < 4; ++rr) {
                char* dst = (char*)xws + gm_base + (size_t)(trow0 + rr) * 8192
                            + ct_off + lane_off;
                *(__bf16*)dst = (__bf16)acc[ct][rr];
            }
        }
    }
}

// ---------------------------------------------------------------------------
// K2: LSTM scan, ONE WAVE per 16-batch group (16 blocks x 64 threads).
// No barriers (single wave). xw staged via global_load_lds DMA into a
// depth-4 LDS ring (8KB/step, 8 x 1KB DMA per step, issued 4 steps ahead;
// counted s_waitcnt vmcnt(24), never 0). Consume: 8 ds_read_b128 + shl/and
// unpack -> acc (VGPR C). 32 MFMA (A = prescaled Ut, resident). Gates
// register-local (rho permutation), bf16 repack -> next B-frags.
// ---------------------------------------------------------------------------
__global__ __launch_bounds__(64, 1)
void k2_scan(const __bf16* __restrict__ xws, const float* __restrict__ U,
             float* __restrict__ hout) {
    const int l  = threadIdx.x & 63;
    const int kq = l >> 4;
    const int m  = l & 15;
    const int b0 = blockIdx.x * 16;

    __shared__ __align__(16) unsigned char ring[4][8192];   // 32KB

    // A-frags: au[tt][ks][j] = sc * U[ks*32 + kq*8 + j][origcol(16tt + m)]
    bf16x8 au[16][2];
#pragma unroll
    for (int tt = 0; tt < 16; ++tt) {
        const int rho = 16 * tt + m;
        const int col = rho_origcol(rho);
        const float sc = ((rho >> 6) == 2) ? 1.f : 0.2f;
#pragma unroll
        for (int ks = 0; ks < 2; ++ks)
#pragma unroll
            for (int j = 0; j < 8; ++j)
                au[tt][ks][j] = (__bf16)(sc * U[(size_t)(ks * 32 + kq * 8 + j) * G4 + col]);
    }

    float c[2][2][4];
    float h[2][2][4];
#pragma unroll
    for (int s = 0; s < 2; ++s)
#pragma unroll
        for (int d2 = 0; d2 < 2; ++d2)
#pragma unroll
            for (int dl = 0; dl < 4; ++dl) { c[s][d2][dl] = 0.f; h[s][d2][dl] = 0.f; }

    bf16x8 bh0 = {};   // h == 0 at t=0
    bf16x8 bh1 = {};

    const char* gl = (const char*)xws + ((size_t)blockIdx.x << 23) + (size_t)l * 16;

    // prime the ring: slots 0..3 <- steps 0..3 (32 DMA outstanding)
#pragma unroll
    for (int d = 0; d < 4; ++d)
#pragma unroll
        for (int tp = 0; tp < 8; ++tp)
            gld_lds16(gl + (size_t)d * 8192 + tp * 1024, &ring[d][tp * 1024]);

    for (int t0 = 0; t0 < Tt; t0 += 4) {
#pragma unroll
        for (int s = 0; s < 4; ++s) {
            const int t = t0 + s;

            // ---- slot s ready when <=24 loads outstanding (3 newer slots)
            asm volatile("s_waitcnt vmcnt(24)" ::: "memory");

            // ---- consume slot s: 8 x ds_read_b128, unpack to acc (exact)
            f32x4v acc[16];
#pragma unroll
            for (int tp = 0; tp < 8; ++tp) {
                const uint4 d = *(const uint4*)&ring[s][tp * 1024 + l * 16];
                acc[2 * tp][0]     = __builtin_bit_cast(float, d.x << 16);
                acc[2 * tp][1]     = __builtin_bit_cast(float, d.x & 0xFFFF0000u);
                acc[2 * tp][2]     = __builtin_bit_cast(float, d.y << 16);
                acc[2 * tp][3]     = __builtin_bit_cast(float, d.y & 0xFFFF0000u);
                acc[2 * tp + 1][0] = __builtin_bit_cast(float, d.z << 16);
                acc[2 * tp + 1][1] = __builtin_bit_cast(float, d.z & 0xFFFF0000u);
                acc[2 * tp + 1][2] = __builtin_bit_cast(float, d.w << 16);
                acc[2 * tp + 1][3] = __builtin_bit_cast(float, d.w & 0xFFFF0000u);
            }

            // ---- reissue slot s for step t+4 (clamped; dead at tail, harmless)
            {
                int tpf = t + 4; if (tpf > Tt - 1) tpf = Tt - 1;
                const char* p = gl + (size_t)tpf * 8192;
#pragma unroll
                for (int tp = 0; tp < 8; ++tp)
                    gld_lds16(p + tp * 1024, &ring[s][tp * 1024]);
            }

            // ---- z' = Ut.h + xw' : 32 MFMA, 16 independent chains of 2
#pragma unroll
            for (int tt = 0; tt < 16; ++tt) {
                acc[tt] = __builtin_amdgcn_mfma_f32_16x16x32_bf16(au[tt][0], bh0, acc[tt], 0, 0, 0);
                acc[tt] = __builtin_amdgcn_mfma_f32_16x16x32_bf16(au[tt][1], bh1, acc[tt], 0, 0, 0);
            }

            // ---- gates: register-local; i,f,o are already 0.2z+0.5
#pragma unroll
            for (int s2 = 0; s2 < 2; ++s2)
#pragma unroll
                for (int d2 = 0; d2 < 2; ++d2) {
                    const int ti = 2 * s2 + d2;
#pragma unroll
                    for (int dl = 0; dl < 4; ++dl) {
                        const float gi = fminf(fmaxf(acc[ti][dl],      0.f), 1.f);  // med3
                        const float gf = fminf(fmaxf(acc[4 + ti][dl],  0.f), 1.f);
                        const float gg = fmaxf(acc[8 + ti][dl], 0.f);
                        const float go = fminf(fmaxf(acc[12 + ti][dl], 0.f), 1.f);
                        const float cc = fmaf(gf, c[s2][d2][dl], gi * gg);
                        c[s2][d2][dl] = cc;
                        h[s2][d2][dl] = go * fmaxf(cc, 0.f);
                    }
                }

            // ---- pack next-step B-frags: bh0 = h[s2=0], bh1 = h[s2=1]
#pragma unroll
            for (int d2 = 0; d2 < 2; ++d2)
#pragma unroll
                for (int dl = 0; dl < 4; ++dl) {
                    bh0[4 * d2 + dl] = (__bf16)h[0][d2][dl];
                    bh1[4 * d2 + dl] = (__bf16)h[1][d2][dl];
                }
        }
    }

    // final h: hidx = 32*s2 + 8*kq + 4*d2 + dl
#pragma unroll
    for (int s2 = 0; s2 < 2; ++s2)
#pragma unroll
        for (int d2 = 0; d2 < 2; ++d2)
#pragma unroll
            for (int dl = 0; dl < 4; ++dl)
                hout[(size_t)(b0 + m) * Hh + 32 * s2 + 8 * kq + 4 * d2 + dl] = h[s2][d2][dl];
}

// ---------------------------------------------------------------------------
// K3: out[r,:] = softmax(h[r,:] @ Wd + bd). One block, thread = batch row.
// ---------------------------------------------------------------------------
__global__ __launch_bounds__(256)
void k3_dense(const float* __restrict__ hin, const float* __restrict__ Wd,
              const float* __restrict__ bd, float* __restrict__ out) {
    __shared__ float wd[Hh * NOUT];
    __shared__ float bds[NOUT];
    for (int i = threadIdx.x; i < Hh * NOUT; i += blockDim.x) wd[i] = Wd[i];
    if (threadIdx.x < NOUT) bds[threadIdx.x] = bd[threadIdx.x];
    __syncthreads();

    const int r = threadIdx.x;
    if (r < Bsz) {
        float hrow[Hh];
#pragma unroll
        for (int j = 0; j < Hh; ++j) hrow[j] = hin[(size_t)r * Hh + j];
        float logits[NOUT];
#pragma unroll
        for (int o = 0; o < NOUT; ++o) {
            float acc = bds[o];
#pragma unroll
            for (int j = 0; j < Hh; ++j) acc = fmaf(hrow[j], wd[j * NOUT + o], acc);
            logits[o] = acc;
        }
        float mx = logits[0];
#pragma unroll
        for (int o = 1; o < NOUT; ++o) mx = fmaxf(mx, logits[o]);
        float s = 0.f;
#pragma unroll
        for (int o = 0; o < NOUT; ++o) { logits[o] = expf(logits[o] - mx); s += logits[o]; }
        const float inv = 1.f / s;
#pragma unroll
        for (int o = 0; o < NOUT; ++o) out[(size_t)r * NOUT + o] = logits[o] * inv;
    }
}

// ---------------------------------------------------------------------------
extern "C" void kernel_launch(void* const* d_in, const int* in_sizes, int n_in,
                              void* d_out, int out_size, void* d_ws, size_t ws_size,
                              hipStream_t stream) {
    const float* x  = (const float*)d_in[0];
    const float* W  = (const float*)d_in[1];
    const float* U  = (const float*)d_in[2];
    const float* b  = (const float*)d_in[3];
    const float* Wd = (const float*)d_in[4];
    const float* bd = (const float*)d_in[5];
    float* out = (float*)d_out;

    const size_t xw_bytes = (size_t)Bsz * Tt * G4 * sizeof(__bf16);   // 128 MiB
    __bf16* xws   = (__bf16*)d_ws;
    float*  hbuf  = (float*)((char*)d_ws + xw_bytes);                 // 64 KB
    __bf16* Wt    = (__bf16*)((char*)hbuf + (size_t)Bsz * Hh * sizeof(float));
    float*  bias2 = (float*)((char*)Wt + (size_t)G4 * Dd * sizeof(__bf16));

    k0_prep<<<G4, Dd, 0, stream>>>(W, b, Wt, bias2);
    k1_mfma<<<(Bsz * Tt) / (16 * K1_RT), 256, 0, stream>>>(x, Wt, bias2, xws);
    k2_scan<<<Bsz / 16, 64, 0, stream>>>(xws, U, hbuf);
    k3_dense<<<1, 256, 0, stream>>>(hbuf, Wd, bd, out);
}